// Round 1
// baseline (592.315 us; speedup 1.0000x reference)
//
#include <hip/hip_runtime.h>
#include <hip/hip_bf16.h>

// Sizes (fixed by the problem)
#define N_   32
#define L_   77
#define CT_  512
#define C_   512
#define HW_  1024
#define HEAD_ 16
#define DH_  32   // C/HEAD

static __device__ __forceinline__ unsigned short f2bf(float f) {
    unsigned int u = __float_as_uint(f);
    unsigned int r = (u + 0x7fffu + ((u >> 16) & 1u)) >> 16;  // RNE
    return (unsigned short)r;
}
static __device__ __forceinline__ float bf2f(unsigned short s) {
    return __uint_as_float(((unsigned int)s) << 16);
}

// ---------------------------------------------------------------------------
// Kernel A: K/V projection.  k[n,o,l] = sum_c Wk[o,c]*tok[n,c,l] + bk[o]
// tok[n,c,l] = token[n*CT*L + c*L + l]  (pure reshape)
// grid = N*8 (o-chunks of 64), block = 256
// ---------------------------------------------------------------------------
__global__ __launch_bounds__(256) void kv_kernel(
    const float* __restrict__ token,
    const float* __restrict__ Wk, const float* __restrict__ bk,
    const float* __restrict__ Wv, const float* __restrict__ bv,
    float* __restrict__ kbuf, float* __restrict__ vbuf)
{
    __shared__ float tokLDS[64][80];   // 64 c x 77 l (padded to 80)

    const int blk = blockIdx.x;
    const int n  = blk >> 3;
    const int o0 = (blk & 7) * 64;
    const int t  = threadIdx.x;
    const int og = t >> 2;        // 0..63  (o_local)
    const int lg = t & 3;         // 0..3
    const int lbase = lg * 20;    // l chunk base: 0,20,40,60 (last chunk has 17 valid)

    float kacc[20], vacc[20];
#pragma unroll
    for (int j = 0; j < 20; ++j) { kacc[j] = 0.f; vacc[j] = 0.f; }

    const float* tokn = token + (size_t)n * (CT_ * L_);
    const int o = o0 + og;
    const float* wkrow = Wk + (size_t)o * CT_;
    const float* wvrow = Wv + (size_t)o * CT_;

    for (int c0 = 0; c0 < CT_; c0 += 64) {
        __syncthreads();
        // 64*77 contiguous floats starting at c0*77
        const float* src = tokn + c0 * L_;
        for (int idx = t; idx < 64 * L_; idx += 256) {
            int cc = idx / L_;
            int l  = idx - cc * L_;
            tokLDS[cc][l] = src[idx];
        }
        __syncthreads();

        for (int cc = 0; cc < 64; ++cc) {
            float wk = wkrow[c0 + cc];
            float wv = wvrow[c0 + cc];
            const float4* row = (const float4*)(&tokLDS[cc][lbase]);
#pragma unroll
            for (int j4 = 0; j4 < 5; ++j4) {
                float4 tv = row[j4];
                kacc[4*j4+0] += wk * tv.x;  vacc[4*j4+0] += wv * tv.x;
                kacc[4*j4+1] += wk * tv.y;  vacc[4*j4+1] += wv * tv.y;
                kacc[4*j4+2] += wk * tv.z;  vacc[4*j4+2] += wv * tv.z;
                kacc[4*j4+3] += wk * tv.w;  vacc[4*j4+3] += wv * tv.w;
            }
        }
    }

    const float bkv = bk[o], bvv = bv[o];
    float* kdst = kbuf + ((size_t)n * C_ + o) * L_;
    float* vdst = vbuf + ((size_t)n * C_ + o) * L_;
    const int lim = (lbase + 20 <= L_) ? 20 : (L_ - lbase);
    for (int j = 0; j < lim; ++j) {
        kdst[lbase + j] = kacc[j] + bkv;
        vdst[lbase + j] = vacc[j] + bvv;
    }
}

// ---------------------------------------------------------------------------
// Kernel B: Q projection. q[n,o,p] = sum_c Wq[o,c]*feature[n,c,p] + bq[o]
// Output stored as bf16 (ushort). grid = N*8*4 (o-tile 64, p-tile 256), block 256
// ---------------------------------------------------------------------------
__global__ __launch_bounds__(256) void q_kernel(
    const float* __restrict__ feature,
    const float* __restrict__ Wq, const float* __restrict__ bq,
    unsigned short* __restrict__ qbuf)
{
    __shared__ float Bt[32][256];  // c-tile x p-tile
    __shared__ float At[32][68];   // c-tile x o-tile (transposed Wq, padded)

    const int blk = blockIdx.x;
    const int pt = blk & 3;
    const int ot = (blk >> 2) & 7;
    const int n  = blk >> 5;
    const int o0 = ot * 64;
    const int p0 = pt * 256;

    const int t  = threadIdx.x;
    const int pl = (t & 63) * 4;        // 4 consecutive p
    const int og = (t >> 6) * 16;       // 16 consecutive o

    float acc[16][4];
#pragma unroll
    for (int i = 0; i < 16; ++i)
#pragma unroll
        for (int j = 0; j < 4; ++j) acc[i][j] = 0.f;

    const float* featn = feature + (size_t)n * C_ * HW_ + p0;

    for (int c0 = 0; c0 < C_; c0 += 32) {
        __syncthreads();
        // Bt: 32 x 256 floats, float4 loads (feature rows contiguous in p)
        for (int idx = t; idx < 32 * 64; idx += 256) {
            int cc = idx >> 6;
            int pp = (idx & 63) * 4;
            *(float4*)&Bt[cc][pp] =
                *(const float4*)&featn[(size_t)(c0 + cc) * HW_ + pp];
        }
        // At[cc][oo] = Wq[o0+oo, c0+cc]; coalesced over cc
        for (int idx = t; idx < 2048; idx += 256) {
            int oo = idx >> 5;
            int cc = idx & 31;
            At[cc][oo] = Wq[(size_t)(o0 + oo) * C_ + (c0 + cc)];
        }
        __syncthreads();

        for (int cc = 0; cc < 32; ++cc) {
            float4 b = *(const float4*)&Bt[cc][pl];
            const float4* arow = (const float4*)&At[cc][og];
            float4 a0 = arow[0], a1 = arow[1], a2 = arow[2], a3 = arow[3];
            const float a[16] = { a0.x,a0.y,a0.z,a0.w, a1.x,a1.y,a1.z,a1.w,
                                  a2.x,a2.y,a2.z,a2.w, a3.x,a3.y,a3.z,a3.w };
#pragma unroll
            for (int i = 0; i < 16; ++i) {
                acc[i][0] += a[i] * b.x;
                acc[i][1] += a[i] * b.y;
                acc[i][2] += a[i] * b.z;
                acc[i][3] += a[i] * b.w;
            }
        }
    }

#pragma unroll
    for (int i = 0; i < 16; ++i) {
        const int o = o0 + og + i;
        const float bqv = bq[o];
        ushort4 pk;
        pk.x = f2bf(acc[i][0] + bqv);
        pk.y = f2bf(acc[i][1] + bqv);
        pk.z = f2bf(acc[i][2] + bqv);
        pk.w = f2bf(acc[i][3] + bqv);
        *(ushort4*)&qbuf[((size_t)n * C_ + o) * HW_ + p0 + pl] = pk;
    }
}

// ---------------------------------------------------------------------------
// Kernel C: attention + residual.
// grid = N*HEAD*4 (p-chunks of 256), block = 256, thread = one spatial pos
// ---------------------------------------------------------------------------
__global__ __launch_bounds__(256) void attn_kernel(
    const float* __restrict__ feature,
    const float* __restrict__ kbuf, const float* __restrict__ vbuf,
    const unsigned short* __restrict__ qbuf,
    float* __restrict__ out)
{
    __shared__ float kl[DH_][80];
    __shared__ float vl[DH_][80];

    const int blk = blockIdx.x;
    const int pc = blk & 3;
    const int h  = (blk >> 2) & 15;
    const int n  = blk >> 6;
    const int p0 = pc * 256;
    const int t  = threadIdx.x;

    const float* ksrc = kbuf + ((size_t)n * C_ + h * DH_) * L_;
    const float* vsrc = vbuf + ((size_t)n * C_ + h * DH_) * L_;
    for (int idx = t; idx < DH_ * L_; idx += 256) {
        int dd = idx / L_;
        int l  = idx - dd * L_;
        kl[dd][l] = ksrc[idx];
        vl[dd][l] = vsrc[idx];
    }
    __syncthreads();

    // load q (bf16 -> f32)
    float q[DH_];
    const unsigned short* qsrc =
        qbuf + ((size_t)n * C_ + h * DH_) * HW_ + p0 + t;
#pragma unroll
    for (int dd = 0; dd < DH_; ++dd) q[dd] = bf2f(qsrc[(size_t)dd * HW_]);

    const float scale = 0.17677669529663687f;  // 1/sqrt(32)

    // pass 1: online max + denominator
    float m = -1e30f, Z = 0.f;
    for (int l = 0; l < L_; ++l) {
        float s = 0.f;
#pragma unroll
        for (int dd = 0; dd < DH_; ++dd) s += q[dd] * kl[dd][l];
        s *= scale;
        float mn = fmaxf(m, s);
        Z = Z * __expf(m - mn) + __expf(s - mn);
        m = mn;
    }
    const float invZ = 1.f / Z;

    // pass 2: recompute scores, accumulate proj
    float proj[DH_];
#pragma unroll
    for (int dd = 0; dd < DH_; ++dd) proj[dd] = 0.f;
    for (int l = 0; l < L_; ++l) {
        float s = 0.f;
#pragma unroll
        for (int dd = 0; dd < DH_; ++dd) s += q[dd] * kl[dd][l];
        s *= scale;
        float c = __expf(s - m) * invZ;
#pragma unroll
        for (int dd = 0; dd < DH_; ++dd) proj[dd] += vl[dd][l] * c;
    }

    const size_t base = ((size_t)n * C_ + h * DH_) * HW_ + p0 + t;
#pragma unroll
    for (int dd = 0; dd < DH_; ++dd)
        out[base + (size_t)dd * HW_] = feature[base + (size_t)dd * HW_] + proj[dd];
}

// ---------------------------------------------------------------------------
extern "C" void kernel_launch(void* const* d_in, const int* in_sizes, int n_in,
                              void* d_out, int out_size, void* d_ws, size_t ws_size,
                              hipStream_t stream)
{
    const float* feature = (const float*)d_in[0];
    const float* token   = (const float*)d_in[1];
    const float* Wv      = (const float*)d_in[2];
    const float* bv      = (const float*)d_in[3];
    const float* Wk      = (const float*)d_in[4];
    const float* bk      = (const float*)d_in[5];
    const float* Wq      = (const float*)d_in[6];
    const float* bq      = (const float*)d_in[7];
    float* out = (float*)d_out;

    // workspace layout
    float* kbuf = (float*)d_ws;                       // N*C*L f32
    float* vbuf = kbuf + (size_t)N_ * C_ * L_;        // N*C*L f32
    unsigned short* qbuf = (unsigned short*)(vbuf + (size_t)N_ * C_ * L_); // N*C*HW bf16

    kv_kernel<<<N_ * 8, 256, 0, stream>>>(token, Wk, bk, Wv, bv, kbuf, vbuf);
    q_kernel<<<N_ * 8 * 4, 256, 0, stream>>>(feature, Wq, bq, qbuf);
    attn_kernel<<<N_ * HEAD_ * 4, 256, 0, stream>>>(feature, kbuf, vbuf, qbuf, out);

    // tuple output: token passthrough
    hipMemcpyAsync(out + (size_t)N_ * C_ * HW_, token,
                   (size_t)N_ * L_ * CT_ * sizeof(float),
                   hipMemcpyDeviceToDevice, stream);
}

// Round 2
// 267.891 us; speedup vs baseline: 2.2110x; 2.2110x over previous
//
#include <hip/hip_runtime.h>
#include <hip/hip_bf16.h>

// Sizes (fixed by the problem)
#define N_   32
#define L_   77
#define CT_  512
#define C_   512
#define HW_  1024
#define HEAD_ 16
#define DH_  32   // C/HEAD

typedef __attribute__((ext_vector_type(8))) short bf16x8;
typedef __attribute__((ext_vector_type(4))) float f32x4;

static __device__ __forceinline__ unsigned short f2bf(float f) {
    unsigned int u = __float_as_uint(f);
    unsigned int r = (u + 0x7fffu + ((u >> 16) & 1u)) >> 16;  // RNE
    return (unsigned short)r;
}
static __device__ __forceinline__ float bf2f(unsigned short s) {
    return __uint_as_float(((unsigned int)s) << 16);
}

// ---------------------------------------------------------------------------
// Kernel A: K/V projection.  k[n,o,l] = sum_c Wk[o,c]*tok[n,c,l] + bk[o]
// tok[n,c,l] = token[n*CT*L + c*L + l]  (pure reshape)
// grid = N*8 (o-chunks of 64), block = 256
// ---------------------------------------------------------------------------
__global__ __launch_bounds__(256) void kv_kernel(
    const float* __restrict__ token,
    const float* __restrict__ Wk, const float* __restrict__ bk,
    const float* __restrict__ Wv, const float* __restrict__ bv,
    float* __restrict__ kbuf, float* __restrict__ vbuf)
{
    __shared__ float tokLDS[64][80];   // 64 c x 77 l (padded to 80)

    const int blk = blockIdx.x;
    const int n  = blk >> 3;
    const int o0 = (blk & 7) * 64;
    const int t  = threadIdx.x;
    const int og = t >> 2;        // 0..63  (o_local)
    const int lg = t & 3;         // 0..3
    const int lbase = lg * 20;    // l chunk base: 0,20,40,60 (last chunk has 17 valid)

    float kacc[20], vacc[20];
#pragma unroll
    for (int j = 0; j < 20; ++j) { kacc[j] = 0.f; vacc[j] = 0.f; }

    const float* tokn = token + (size_t)n * (CT_ * L_);
    const int o = o0 + og;
    const float* wkrow = Wk + (size_t)o * CT_;
    const float* wvrow = Wv + (size_t)o * CT_;

    for (int c0 = 0; c0 < CT_; c0 += 64) {
        __syncthreads();
        const float* src = tokn + c0 * L_;
        for (int idx = t; idx < 64 * L_; idx += 256) {
            int cc = idx / L_;
            int l  = idx - cc * L_;
            tokLDS[cc][l] = src[idx];
        }
        __syncthreads();

        for (int cc = 0; cc < 64; ++cc) {
            float wk = wkrow[c0 + cc];
            float wv = wvrow[c0 + cc];
            const float4* row = (const float4*)(&tokLDS[cc][lbase]);
#pragma unroll
            for (int j4 = 0; j4 < 5; ++j4) {
                float4 tv = row[j4];
                kacc[4*j4+0] += wk * tv.x;  vacc[4*j4+0] += wv * tv.x;
                kacc[4*j4+1] += wk * tv.y;  vacc[4*j4+1] += wv * tv.y;
                kacc[4*j4+2] += wk * tv.z;  vacc[4*j4+2] += wv * tv.z;
                kacc[4*j4+3] += wk * tv.w;  vacc[4*j4+3] += wv * tv.w;
            }
        }
    }

    const float bkv = bk[o], bvv = bv[o];
    float* kdst = kbuf + ((size_t)n * C_ + o) * L_;
    float* vdst = vbuf + ((size_t)n * C_ + o) * L_;
    const int lim = (lbase + 20 <= L_) ? 20 : (L_ - lbase);
    for (int j = 0; j < lim; ++j) {
        kdst[lbase + j] = kacc[j] + bkv;
        vdst[lbase + j] = vacc[j] + bvv;
    }
}

// ---------------------------------------------------------------------------
// Kernel B: Q projection via bf16 MFMA.
// q[n,o,p] = sum_c Wq[o,c]*feature[n,c,p] + bq[o], stored bf16.
// Tile 128(o) x 128(p), BK=64. 4 waves, each 64x64 via 4x4 frags of 16x16x32.
// A_lds[o][c], B_lds[p][c] bf16, both XOR-swizzled: byte ^= ((row&7)<<4).
// grid = N * 4(ot) * 8(pt), block 256.
// ---------------------------------------------------------------------------
__global__ __launch_bounds__(256) void qmfma_kernel(
    const float* __restrict__ feature,
    const float* __restrict__ Wq, const float* __restrict__ bq,
    unsigned short* __restrict__ qbuf)
{
    __shared__ unsigned char Ab[128 * 128];  // 128 rows x 64 bf16 = 128B/row
    __shared__ unsigned char Bb[128 * 128];

    const int blk = blockIdx.x;
    const int pt = blk & 7;
    const int ot = (blk >> 3) & 3;
    const int n  = blk >> 5;
    const int o0 = ot * 128, p0 = pt * 128;
    const int t = threadIdx.x;
    const int lane = t & 63, w = t >> 6;
    const int wr = w >> 1, wc = w & 1;     // wave sub-tile (64x64)

    f32x4 acc[4][4];
#pragma unroll
    for (int i = 0; i < 4; ++i)
#pragma unroll
        for (int j = 0; j < 4; ++j) acc[i][j] = (f32x4){0.f, 0.f, 0.f, 0.f};

    const float* featn = feature + (size_t)n * C_ * HW_;

    for (int c0 = 0; c0 < C_; c0 += 64) {
        __syncthreads();
        // stage A: Wq[o0+row][c0+c4..c4+3] -> Ab[row][c4] (bf16, swizzled)
#pragma unroll
        for (int s = 0; s < 8; ++s) {
            int idx = t + s * 256;           // 0..2047
            int row = idx >> 4;              // 0..127
            int c4  = (idx & 15) * 4;        // 0..60
            float4 f = *(const float4*)&Wq[(size_t)(o0 + row) * C_ + c0 + c4];
            ushort4 h; h.x = f2bf(f.x); h.y = f2bf(f.y); h.z = f2bf(f.z); h.w = f2bf(f.w);
            int ba = row * 128 + ((c4 * 2) ^ ((row & 7) << 4));
            *(ushort4*)(Ab + ba) = h;
        }
        // stage B: feat[c][p] -> Bb[p][c] (transpose via 4 strided scalar loads)
        {
            int p    = t & 127;
            int half = t >> 7;               // 0/1 -> c 0..31 / 32..63
#pragma unroll
            for (int it = 0; it < 8; ++it) {
                int cl = half * 32 + it * 4;
                const float* src = featn + (size_t)(c0 + cl) * HW_ + p0 + p;
                float f0 = src[0];
                float f1 = src[HW_];
                float f2 = src[2 * HW_];
                float f3 = src[3 * HW_];
                ushort4 h; h.x = f2bf(f0); h.y = f2bf(f1); h.z = f2bf(f2); h.w = f2bf(f3);
                int ba = p * 128 + ((cl * 2) ^ ((p & 7) << 4));
                *(ushort4*)(Bb + ba) = h;
            }
        }
        __syncthreads();

#pragma unroll
        for (int ks = 0; ks < 2; ++ks) {
            const int kb = ks * 64 + (lane >> 4) * 16;  // byte offset of this lane's k8
            bf16x8 a[4], b[4];
#pragma unroll
            for (int i = 0; i < 4; ++i) {
                int row = wr * 64 + i * 16 + (lane & 15);
                a[i] = *(const bf16x8*)(Ab + row * 128 + (kb ^ ((row & 7) << 4)));
            }
#pragma unroll
            for (int j = 0; j < 4; ++j) {
                int prow = wc * 64 + j * 16 + (lane & 15);
                b[j] = *(const bf16x8*)(Bb + prow * 128 + (kb ^ ((prow & 7) << 4)));
            }
#pragma unroll
            for (int i = 0; i < 4; ++i)
#pragma unroll
                for (int j = 0; j < 4; ++j)
                    acc[i][j] = __builtin_amdgcn_mfma_f32_16x16x32_bf16(
                        a[i], b[j], acc[i][j], 0, 0, 0);
        }
    }

    // epilogue: D col = lane&15 (p), row = (lane>>4)*4 + r (o)   [HW-verified map]
#pragma unroll
    for (int i = 0; i < 4; ++i) {
#pragma unroll
        for (int r = 0; r < 4; ++r) {
            int o = o0 + wr * 64 + i * 16 + (lane >> 4) * 4 + r;
            float bias = bq[o];
#pragma unroll
            for (int j = 0; j < 4; ++j) {
                int p = p0 + wc * 64 + j * 16 + (lane & 15);
                qbuf[((size_t)n * C_ + o) * HW_ + p] = f2bf(acc[i][j][r] + bias);
            }
        }
    }
}

// ---------------------------------------------------------------------------
// Kernel C: attention + residual, v2.
// kT/vT rows in LDS (broadcast b128 reads), 2 p per thread, single pass
// online softmax with defer-max (THR=8).
// grid = N*HEAD*2 (p-chunks of 512), block = 256
// ---------------------------------------------------------------------------
__global__ __launch_bounds__(256) void attn_kernel(
    const float* __restrict__ feature,
    const float* __restrict__ kbuf, const float* __restrict__ vbuf,
    const unsigned short* __restrict__ qbuf,
    float* __restrict__ out)
{
    __shared__ float kT[L_][36];   // row l: 32 d contiguous (16B-aligned rows)
    __shared__ float vT[L_][36];

    const int blk = blockIdx.x;
    const int pc = blk & 1;
    const int h  = (blk >> 1) & 15;
    const int n  = blk >> 5;
    const int p0 = pc * 512;
    const int t  = threadIdx.x;

    // transpose-stage k,v: [d][l] global -> [l][d] LDS
    const float* ksrc = kbuf + ((size_t)n * C_ + h * DH_) * L_;
    const float* vsrc = vbuf + ((size_t)n * C_ + h * DH_) * L_;
    for (int idx = t; idx < DH_ * L_; idx += 256) {
        int dd = idx / L_;
        int l  = idx - dd * L_;
        kT[l][dd] = ksrc[idx];
        vT[l][dd] = vsrc[idx];
    }
    __syncthreads();

    // load q for two positions: p0+t and p0+t+256 (bf16 -> f32)
    float q0[DH_], q1[DH_];
    const unsigned short* qb = qbuf + ((size_t)n * C_ + h * DH_) * HW_ + p0 + t;
#pragma unroll
    for (int dd = 0; dd < DH_; ++dd) {
        q0[dd] = bf2f(qb[(size_t)dd * HW_]);
        q1[dd] = bf2f(qb[(size_t)dd * HW_ + 256]);
    }

    const float scale = 0.17677669529663687f;  // 1/sqrt(32)

    float m0 = -3.0e38f, Z0 = 0.f;
    float m1 = -3.0e38f, Z1 = 0.f;
    float proj0[DH_], proj1[DH_];
#pragma unroll
    for (int dd = 0; dd < DH_; ++dd) { proj0[dd] = 0.f; proj1[dd] = 0.f; }

    for (int l = 0; l < L_; ++l) {
        const float4* kr = (const float4*)(&kT[l][0]);
        float s0 = 0.f, s1 = 0.f;
#pragma unroll
        for (int d4 = 0; d4 < 8; ++d4) {
            float4 kk = kr[d4];
            s0 += q0[4*d4+0] * kk.x; s1 += q1[4*d4+0] * kk.x;
            s0 += q0[4*d4+1] * kk.y; s1 += q1[4*d4+1] * kk.y;
            s0 += q0[4*d4+2] * kk.z; s1 += q1[4*d4+2] * kk.z;
            s0 += q0[4*d4+3] * kk.w; s1 += q1[4*d4+3] * kk.w;
        }
        s0 *= scale; s1 *= scale;

        // defer-max: only rescale when the max grows by > 8
        if (s0 > m0 + 8.f) {
            float f = __expf(m0 - s0);
            Z0 *= f;
#pragma unroll
            for (int dd = 0; dd < DH_; ++dd) proj0[dd] *= f;
            m0 = s0;
        }
        if (s1 > m1 + 8.f) {
            float f = __expf(m1 - s1);
            Z1 *= f;
#pragma unroll
            for (int dd = 0; dd < DH_; ++dd) proj1[dd] *= f;
            m1 = s1;
        }
        float e0 = __expf(s0 - m0);
        float e1 = __expf(s1 - m1);
        Z0 += e0; Z1 += e1;

        const float4* vr = (const float4*)(&vT[l][0]);
#pragma unroll
        for (int d4 = 0; d4 < 8; ++d4) {
            float4 vv = vr[d4];
            proj0[4*d4+0] += e0 * vv.x; proj1[4*d4+0] += e1 * vv.x;
            proj0[4*d4+1] += e0 * vv.y; proj1[4*d4+1] += e1 * vv.y;
            proj0[4*d4+2] += e0 * vv.z; proj1[4*d4+2] += e1 * vv.z;
            proj0[4*d4+3] += e0 * vv.w; proj1[4*d4+3] += e1 * vv.w;
        }
    }

    const float iZ0 = 1.f / Z0, iZ1 = 1.f / Z1;
    const size_t base = ((size_t)n * C_ + h * DH_) * HW_ + p0 + t;
#pragma unroll
    for (int dd = 0; dd < DH_; ++dd) {
        size_t ix = base + (size_t)dd * HW_;
        out[ix]       = feature[ix]       + proj0[dd] * iZ0;
        out[ix + 256] = feature[ix + 256] + proj1[dd] * iZ1;
    }
}

// ---------------------------------------------------------------------------
extern "C" void kernel_launch(void* const* d_in, const int* in_sizes, int n_in,
                              void* d_out, int out_size, void* d_ws, size_t ws_size,
                              hipStream_t stream)
{
    const float* feature = (const float*)d_in[0];
    const float* token   = (const float*)d_in[1];
    const float* Wv      = (const float*)d_in[2];
    const float* bv      = (const float*)d_in[3];
    const float* Wk      = (const float*)d_in[4];
    const float* bk      = (const float*)d_in[5];
    const float* Wq      = (const float*)d_in[6];
    const float* bq      = (const float*)d_in[7];
    float* out = (float*)d_out;

    // workspace layout
    float* kbuf = (float*)d_ws;                       // N*C*L f32
    float* vbuf = kbuf + (size_t)N_ * C_ * L_;        // N*C*L f32
    unsigned short* qbuf = (unsigned short*)(vbuf + (size_t)N_ * C_ * L_); // N*C*HW bf16

    kv_kernel<<<N_ * 8, 256, 0, stream>>>(token, Wk, bk, Wv, bv, kbuf, vbuf);
    qmfma_kernel<<<N_ * 32, 256, 0, stream>>>(feature, Wq, bq, qbuf);
    attn_kernel<<<N_ * HEAD_ * 2, 256, 0, stream>>>(feature, kbuf, vbuf, qbuf, out);

    // tuple output: token passthrough
    hipMemcpyAsync(out + (size_t)N_ * C_ * HW_, token,
                   (size_t)N_ * L_ * CT_ * sizeof(float),
                   hipMemcpyDeviceToDevice, stream);
}

// Round 3
// 155.452 us; speedup vs baseline: 3.8103x; 1.7233x over previous
//
#include <hip/hip_runtime.h>
#include <hip/hip_bf16.h>

// Sizes (fixed by the problem)
#define N_   32
#define L_   77
#define CT_  512
#define C_   512
#define HW_  1024
#define HEAD_ 16
#define DH_  32   // C/HEAD
#define NL_  (N_ * L_)     // 2464
#define NLP_ 2496          // padded to 39*64

typedef __attribute__((ext_vector_type(8))) short bf16x8;
typedef __attribute__((ext_vector_type(4))) float f32x4;

static __device__ __forceinline__ unsigned short f2bf(float f) {
    unsigned int u = __float_as_uint(f);
    unsigned int r = (u + 0x7fffu + ((u >> 16) & 1u)) >> 16;  // RNE
    return (unsigned short)r;
}
static __device__ __forceinline__ float bf2f(unsigned short s) {
    return __uint_as_float(((unsigned int)s) << 16);
}

// ---------------------------------------------------------------------------
// Prep: token -> tokT[nl][c] bf16 (transpose), Wk/Wv -> Wkv[1024][512] bf16,
// bk/bv -> bkv[1024] f32.  grid = 288 (256 transpose + 32 W-convert)
// ---------------------------------------------------------------------------
__global__ __launch_bounds__(256) void prep_kernel(
    const float* __restrict__ token,
    const float* __restrict__ Wk, const float* __restrict__ bk,
    const float* __restrict__ Wv, const float* __restrict__ bv,
    unsigned short* __restrict__ tokT, unsigned short* __restrict__ Wkv,
    float* __restrict__ bkv)
{
    const int blk = blockIdx.x;
    const int t = threadIdx.x;
    if (blk < 256) {
        __shared__ float tile[64][81];   // 81-pad: transpose reads 2-way max
        const int n = blk >> 3, c0 = (blk & 7) * 64;
        const float* src = token + (size_t)n * (CT_ * L_) + (size_t)c0 * L_;
        for (int idx = t; idx < 64 * L_; idx += 256) {
            int cc = idx / L_, l = idx - cc * L_;
            tile[cc][l] = src[idx];
        }
        __syncthreads();
        for (int idx = t; idx < L_ * 16; idx += 256) {
            int l = idx >> 4, cq = (idx & 15) * 4;
            ushort4 h;
            h.x = f2bf(tile[cq + 0][l]);
            h.y = f2bf(tile[cq + 1][l]);
            h.z = f2bf(tile[cq + 2][l]);
            h.w = f2bf(tile[cq + 3][l]);
            *(ushort4*)&tokT[((size_t)(n * L_ + l)) * 512 + c0 + cq] = h;
        }
    } else {
        const int wb = blk - 256;       // 0..31, each handles 32 m-rows
        const int m0 = wb * 32;
        for (int idx = t; idx < 32 * 128; idx += 256) {
            int mr = idx >> 7, c4 = (idx & 127) * 4;
            int m = m0 + mr;
            const float* src = (m < 512) ? (Wk + (size_t)m * 512 + c4)
                                         : (Wv + (size_t)(m - 512) * 512 + c4);
            float4 f = *(const float4*)src;
            ushort4 h; h.x = f2bf(f.x); h.y = f2bf(f.y); h.z = f2bf(f.z); h.w = f2bf(f.w);
            *(ushort4*)&Wkv[(size_t)m * 512 + c4] = h;
        }
        if (wb == 0) {
            for (int idx = t; idx < 1024; idx += 256)
                bkv[idx] = (idx < 512) ? bk[idx] : bv[idx - 512];
        }
    }
}

// ---------------------------------------------------------------------------
// KV GEMM via bf16 MFMA: kvbuf[nl][m] = sum_c Wkv[m][c]*tokT[nl][c] + bkv[m]
// Tile 128(m) x 64(nl), BK=64, 4 waves as 2x2, each 64(m) x 32(nl).
// grid = 8 * 39 = 312
// ---------------------------------------------------------------------------
__global__ __launch_bounds__(256) void kvgemm_kernel(
    const unsigned short* __restrict__ tokT,
    const unsigned short* __restrict__ Wkv,
    const float* __restrict__ bkv,
    float* __restrict__ kvbuf)
{
    __shared__ unsigned char Ab[128 * 128];  // 128 m-rows x 64 c bf16, swizzled
    __shared__ unsigned char Bb[64 * 128];   // 64 nl-rows x 64 c bf16, swizzled

    const int blk = blockIdx.x;
    const int mt = blk / 39, nt = blk % 39;
    const int m0 = mt * 128, nl0 = nt * 64;
    const int t = threadIdx.x;
    const int lane = t & 63, w = t >> 6;
    const int wr = w >> 1, wc = w & 1;

    f32x4 acc[4][2];
#pragma unroll
    for (int i = 0; i < 4; ++i)
#pragma unroll
        for (int j = 0; j < 2; ++j) acc[i][j] = (f32x4){0.f, 0.f, 0.f, 0.f};

    for (int c0 = 0; c0 < 512; c0 += 64) {
        __syncthreads();
#pragma unroll
        for (int s = 0; s < 4; ++s) {
            int idx = t + s * 256;
            int row = idx >> 3, k8 = idx & 7;
            bf16x8 v = *(const bf16x8*)&Wkv[(size_t)(m0 + row) * 512 + c0 + k8 * 8];
            *(bf16x8*)(Ab + row * 128 + ((k8 * 16) ^ ((row & 7) << 4))) = v;
        }
#pragma unroll
        for (int s = 0; s < 2; ++s) {
            int idx = t + s * 256;
            int row = idx >> 3, k8 = idx & 7;
            bf16x8 v = *(const bf16x8*)&tokT[(size_t)(nl0 + row) * 512 + c0 + k8 * 8];
            *(bf16x8*)(Bb + row * 128 + ((k8 * 16) ^ ((row & 7) << 4))) = v;
        }
        __syncthreads();

#pragma unroll
        for (int ks = 0; ks < 2; ++ks) {
            const int kb = ks * 64 + (lane >> 4) * 16;
            bf16x8 a[4], b[2];
#pragma unroll
            for (int i = 0; i < 4; ++i) {
                int row = wr * 64 + i * 16 + (lane & 15);
                a[i] = *(const bf16x8*)(Ab + row * 128 + (kb ^ ((row & 7) << 4)));
            }
#pragma unroll
            for (int j = 0; j < 2; ++j) {
                int row = wc * 32 + j * 16 + (lane & 15);
                b[j] = *(const bf16x8*)(Bb + row * 128 + (kb ^ ((row & 7) << 4)));
            }
#pragma unroll
            for (int i = 0; i < 4; ++i)
#pragma unroll
                for (int j = 0; j < 2; ++j)
                    acc[i][j] = __builtin_amdgcn_mfma_f32_16x16x32_bf16(
                        a[i], b[j], acc[i][j], 0, 0, 0);
        }
    }

    // D: col(nl) = lane&15, row(m) = (lane>>4)*4 + r  -> float4 store per frag
#pragma unroll
    for (int i = 0; i < 4; ++i) {
        int m = m0 + wr * 64 + i * 16 + (lane >> 4) * 4;
        float4 bias = *(const float4*)&bkv[m];
#pragma unroll
        for (int j = 0; j < 2; ++j) {
            int nl = nl0 + wc * 32 + j * 16 + (lane & 15);
            float4 o;
            o.x = acc[i][j][0] + bias.x;
            o.y = acc[i][j][1] + bias.y;
            o.z = acc[i][j][2] + bias.z;
            o.w = acc[i][j][3] + bias.w;
            *(float4*)&kvbuf[(size_t)nl * 1024 + m] = o;
        }
    }
}

// ---------------------------------------------------------------------------
// Kernel B: Q projection via bf16 MFMA (unchanged from R2).
// ---------------------------------------------------------------------------
__global__ __launch_bounds__(256) void qmfma_kernel(
    const float* __restrict__ feature,
    const float* __restrict__ Wq, const float* __restrict__ bq,
    unsigned short* __restrict__ qbuf)
{
    __shared__ unsigned char Ab[128 * 128];
    __shared__ unsigned char Bb[128 * 128];

    const int blk = blockIdx.x;
    const int pt = blk & 7;
    const int ot = (blk >> 3) & 3;
    const int n  = blk >> 5;
    const int o0 = ot * 128, p0 = pt * 128;
    const int t = threadIdx.x;
    const int lane = t & 63, w = t >> 6;
    const int wr = w >> 1, wc = w & 1;

    f32x4 acc[4][4];
#pragma unroll
    for (int i = 0; i < 4; ++i)
#pragma unroll
        for (int j = 0; j < 4; ++j) acc[i][j] = (f32x4){0.f, 0.f, 0.f, 0.f};

    const float* featn = feature + (size_t)n * C_ * HW_;

    for (int c0 = 0; c0 < C_; c0 += 64) {
        __syncthreads();
#pragma unroll
        for (int s = 0; s < 8; ++s) {
            int idx = t + s * 256;
            int row = idx >> 4;
            int c4  = (idx & 15) * 4;
            float4 f = *(const float4*)&Wq[(size_t)(o0 + row) * C_ + c0 + c4];
            ushort4 h; h.x = f2bf(f.x); h.y = f2bf(f.y); h.z = f2bf(f.z); h.w = f2bf(f.w);
            *(ushort4*)(Ab + row * 128 + ((c4 * 2) ^ ((row & 7) << 4))) = h;
        }
        {
            int p    = t & 127;
            int half = t >> 7;
#pragma unroll
            for (int it = 0; it < 8; ++it) {
                int cl = half * 32 + it * 4;
                const float* src = featn + (size_t)(c0 + cl) * HW_ + p0 + p;
                float f0 = src[0];
                float f1 = src[HW_];
                float f2 = src[2 * HW_];
                float f3 = src[3 * HW_];
                ushort4 h; h.x = f2bf(f0); h.y = f2bf(f1); h.z = f2bf(f2); h.w = f2bf(f3);
                *(ushort4*)(Bb + p * 128 + ((cl * 2) ^ ((p & 7) << 4))) = h;
            }
        }
        __syncthreads();

#pragma unroll
        for (int ks = 0; ks < 2; ++ks) {
            const int kb = ks * 64 + (lane >> 4) * 16;
            bf16x8 a[4], b[4];
#pragma unroll
            for (int i = 0; i < 4; ++i) {
                int row = wr * 64 + i * 16 + (lane & 15);
                a[i] = *(const bf16x8*)(Ab + row * 128 + (kb ^ ((row & 7) << 4)));
            }
#pragma unroll
            for (int j = 0; j < 4; ++j) {
                int prow = wc * 64 + j * 16 + (lane & 15);
                b[j] = *(const bf16x8*)(Bb + prow * 128 + (kb ^ ((prow & 7) << 4)));
            }
#pragma unroll
            for (int i = 0; i < 4; ++i)
#pragma unroll
                for (int j = 0; j < 4; ++j)
                    acc[i][j] = __builtin_amdgcn_mfma_f32_16x16x32_bf16(
                        a[i], b[j], acc[i][j], 0, 0, 0);
        }
    }

#pragma unroll
    for (int i = 0; i < 4; ++i) {
#pragma unroll
        for (int r = 0; r < 4; ++r) {
            int o = o0 + wr * 64 + i * 16 + (lane >> 4) * 4 + r;
            float bias = bq[o];
#pragma unroll
            for (int j = 0; j < 4; ++j) {
                int p = p0 + wc * 64 + j * 16 + (lane & 15);
                qbuf[((size_t)n * C_ + o) * HW_ + p] = f2bf(acc[i][j][r] + bias);
            }
        }
    }
}

// ---------------------------------------------------------------------------
// Kernel C: attention + residual (kvbuf [nl][1024] layout; math unchanged).
// grid = N*HEAD*2 (p-chunks of 512), block = 256
// ---------------------------------------------------------------------------
__global__ __launch_bounds__(256) void attn_kernel(
    const float* __restrict__ feature,
    const float* __restrict__ kvbuf,
    const unsigned short* __restrict__ qbuf,
    float* __restrict__ out)
{
    __shared__ float kT[L_][36];
    __shared__ float vT[L_][36];

    const int blk = blockIdx.x;
    const int pc = blk & 1;
    const int h  = (blk >> 1) & 15;
    const int n  = blk >> 5;
    const int p0 = pc * 512;
    const int t  = threadIdx.x;

    // stage k,v: kvbuf row nl=n*77+l, k at col h*32, v at col 512+h*32
    const float* kvb = kvbuf + (size_t)(n * L_) * 1024 + h * DH_;
    for (int idx = t; idx < L_ * 8; idx += 256) {
        int l = idx >> 3, d4 = (idx & 7) * 4;
        *(float4*)&kT[l][d4] = *(const float4*)&kvb[(size_t)l * 1024 + d4];
        *(float4*)&vT[l][d4] = *(const float4*)&kvb[(size_t)l * 1024 + 512 + d4];
    }
    __syncthreads();

    float q0[DH_], q1[DH_];
    const unsigned short* qb = qbuf + ((size_t)n * C_ + h * DH_) * HW_ + p0 + t;
#pragma unroll
    for (int dd = 0; dd < DH_; ++dd) {
        q0[dd] = bf2f(qb[(size_t)dd * HW_]);
        q1[dd] = bf2f(qb[(size_t)dd * HW_ + 256]);
    }

    const float scale = 0.17677669529663687f;  // 1/sqrt(32)

    float m0 = -3.0e38f, Z0 = 0.f;
    float m1 = -3.0e38f, Z1 = 0.f;
    float proj0[DH_], proj1[DH_];
#pragma unroll
    for (int dd = 0; dd < DH_; ++dd) { proj0[dd] = 0.f; proj1[dd] = 0.f; }

    for (int l = 0; l < L_; ++l) {
        const float4* kr = (const float4*)(&kT[l][0]);
        float s0 = 0.f, s1 = 0.f;
#pragma unroll
        for (int d4 = 0; d4 < 8; ++d4) {
            float4 kk = kr[d4];
            s0 += q0[4*d4+0] * kk.x; s1 += q1[4*d4+0] * kk.x;
            s0 += q0[4*d4+1] * kk.y; s1 += q1[4*d4+1] * kk.y;
            s0 += q0[4*d4+2] * kk.z; s1 += q1[4*d4+2] * kk.z;
            s0 += q0[4*d4+3] * kk.w; s1 += q1[4*d4+3] * kk.w;
        }
        s0 *= scale; s1 *= scale;

        if (s0 > m0 + 8.f) {
            float f = __expf(m0 - s0);
            Z0 *= f;
#pragma unroll
            for (int dd = 0; dd < DH_; ++dd) proj0[dd] *= f;
            m0 = s0;
        }
        if (s1 > m1 + 8.f) {
            float f = __expf(m1 - s1);
            Z1 *= f;
#pragma unroll
            for (int dd = 0; dd < DH_; ++dd) proj1[dd] *= f;
            m1 = s1;
        }
        float e0 = __expf(s0 - m0);
        float e1 = __expf(s1 - m1);
        Z0 += e0; Z1 += e1;

        const float4* vr = (const float4*)(&vT[l][0]);
#pragma unroll
        for (int d4 = 0; d4 < 8; ++d4) {
            float4 vv = vr[d4];
            proj0[4*d4+0] += e0 * vv.x; proj1[4*d4+0] += e1 * vv.x;
            proj0[4*d4+1] += e0 * vv.y; proj1[4*d4+1] += e1 * vv.y;
            proj0[4*d4+2] += e0 * vv.z; proj1[4*d4+2] += e1 * vv.z;
            proj0[4*d4+3] += e0 * vv.w; proj1[4*d4+3] += e1 * vv.w;
        }
    }

    const float iZ0 = 1.f / Z0, iZ1 = 1.f / Z1;
    const size_t base = ((size_t)n * C_ + h * DH_) * HW_ + p0 + t;
#pragma unroll
    for (int dd = 0; dd < DH_; ++dd) {
        size_t ix = base + (size_t)dd * HW_;
        out[ix]       = feature[ix]       + proj0[dd] * iZ0;
        out[ix + 256] = feature[ix + 256] + proj1[dd] * iZ1;
    }
}

// ---------------------------------------------------------------------------
extern "C" void kernel_launch(void* const* d_in, const int* in_sizes, int n_in,
                              void* d_out, int out_size, void* d_ws, size_t ws_size,
                              hipStream_t stream)
{
    const float* feature = (const float*)d_in[0];
    const float* token   = (const float*)d_in[1];
    const float* Wv      = (const float*)d_in[2];
    const float* bv      = (const float*)d_in[3];
    const float* Wk      = (const float*)d_in[4];
    const float* bk      = (const float*)d_in[5];
    const float* Wq      = (const float*)d_in[6];
    const float* bq      = (const float*)d_in[7];
    float* out = (float*)d_out;

    // workspace layout (all 16B-aligned)
    float* kvbuf = (float*)d_ws;                                   // NLP_*1024 f32
    unsigned short* tokT = (unsigned short*)(kvbuf + (size_t)NLP_ * 1024);  // NLP_*512 bf16
    unsigned short* Wkv  = tokT + (size_t)NLP_ * 512;              // 1024*512 bf16
    float* bkv = (float*)(Wkv + (size_t)1024 * 512);               // 1024 f32
    unsigned short* qbuf = (unsigned short*)(bkv + 1024);          // N*C*HW bf16

    prep_kernel<<<288, 256, 0, stream>>>(token, Wk, bk, Wv, bv, tokT, Wkv, bkv);
    kvgemm_kernel<<<312, 256, 0, stream>>>(tokT, Wkv, bkv, kvbuf);
    qmfma_kernel<<<N_ * 32, 256, 0, stream>>>(feature, Wq, bq, qbuf);
    attn_kernel<<<N_ * HEAD_ * 2, 256, 0, stream>>>(feature, kvbuf, qbuf, out);

    // tuple output: token passthrough
    hipMemcpyAsync(out + (size_t)N_ * C_ * HW_, token,
                   (size_t)N_ * L_ * CT_ * sizeof(float),
                   hipMemcpyDeviceToDevice, stream);
}